// Round 1
// baseline (1749.681 us; speedup 1.0000x reference)
//
#include <hip/hip_runtime.h>
#include <hip/hip_bf16.h>
#include <math.h>

// ---------------- problem constants ----------------
#define N_BATCH 2
#define HH 50
#define WW 84
#define NPIX (HH*WW)           // 4200
#define KA (NPIX*9)            // 37800
#define N_PRE 6000
#define N_POST 300
#define NMS_T 0.7f
#define NEGV (-1e9f)
#define NWORDS 94              // ceil(6000/64)

// d_out offsets (floats)
#define OFF_LOCS   0
#define OFF_SCORES (N_BATCH*KA*4)                  // 302400
#define OFF_ROIS   (OFF_SCORES + N_BATCH*KA*2)     // 453600
#define OFF_RIDX   (OFF_ROIS + N_BATCH*N_POST*4)   // 456000
#define OFF_ANCH   (OFF_RIDX + N_BATCH*N_POST)     // 456600

// ws offsets (bytes), all 16B aligned
#define WS_HID    0ull
#define WS_FG     17203200ull
#define WS_ROI    17505600ull
#define WS_ITEMS  18715200ull
#define WS_SITEMS 19320000ull
#define WS_SBOX   19416000ull
#define WS_MASK   19608000ull

typedef unsigned long long u64;
typedef unsigned u32;

// ---------------- anchors ----------------
__global__ void k_anchor(float* __restrict__ out) {
  int k = blockIdx.x * 256 + threadIdx.x;
  if (k >= KA) return;
  int a = k % 9; int pj = k / 9; int j = pj % WW; int i = pj / WW;
  int ri = a / 3, si = a % 3;
  double ratio = (ri == 0) ? 0.5 : ((ri == 1) ? 1.0 : 2.0);
  double scale = (si == 0) ? 8.0 : ((si == 1) ? 16.0 : 32.0);
  double h = 16.0 * scale * sqrt(ratio);
  double w = 16.0 * scale * sqrt(1.0 / ratio);
  float y1 = (float)(8.0 - h * 0.5), x1 = (float)(8.0 - w * 0.5);
  float y2 = (float)(8.0 + h * 0.5), x2 = (float)(8.0 + w * 0.5);
  float sy = (float)(i * 16), sx = (float)(j * 16);
  ((float4*)out)[OFF_ANCH / 4 + k] = make_float4(sy + y1, sx + x1, sy + y2, sx + x2);
}

// ---------------- conv1 3x3 512->512 + relu ----------------
// block: 64 ocs x 84 pixels (one output row), 256 threads, thread = (oc, 21-px run)
__global__ __launch_bounds__(256) void k_conv1(const float* __restrict__ x,
    const float* __restrict__ w, const float* __restrict__ bias,
    float* __restrict__ hid) {
  const int ocb = blockIdx.x;   // 0..7
  const int oh  = blockIdx.y;   // 0..49
  const int n   = blockIdx.z;   // 0..1
  const int tid = threadIdx.x;
  const int ocl = tid >> 2;     // 0..63
  const int g   = tid & 3;      // 0..3
  const int ow0 = g * 21;
  __shared__ float lx[8 * 3 * 88];
  __shared__ float lw[64 * 73];
  float acc[21];
#pragma unroll
  for (int p = 0; p < 21; p++) acc[p] = 0.f;
  const int oc = ocb * 64 + ocl;

  for (int ic0 = 0; ic0 < 512; ic0 += 8) {
    // stage input rows (with +-1 col pad, row-OOB -> 0)
    for (int idx = tid; idx < 8 * 3 * 88; idx += 256) {
      int ic = idx / 264; int rem = idx % 264; int ky = rem / 88; int col = rem % 88;
      int y = oh + ky - 1; int ow = col - 1;
      float v = 0.f;
      if ((unsigned)y < 50u && (unsigned)ow < 84u)
        v = x[((size_t)(n * 512 + ic0 + ic) * 50 + y) * 84 + ow];
      lx[(ic * 3 + ky) * 88 + col] = v;
    }
    // stage weights: 64 oc x (8 ic * 9), padded stride 73
    for (int idx = tid; idx < 64 * 72; idx += 256) {
      int o = idx / 72; int r = idx % 72;
      lw[o * 73 + r] = w[(size_t)(ocb * 64 + o) * 4608 + ic0 * 9 + r];
    }
    __syncthreads();
#pragma unroll 2
    for (int ic = 0; ic < 8; ic++) {
#pragma unroll
      for (int ky = 0; ky < 3; ky++) {
        float xv[23];
        const float* lp = &lx[(ic * 3 + ky) * 88 + ow0];
#pragma unroll
        for (int jj = 0; jj < 23; jj++) xv[jj] = lp[jj];
        const float* wp = &lw[ocl * 73 + ic * 9 + ky * 3];
#pragma unroll
        for (int kx = 0; kx < 3; kx++) {
          float wv = wp[kx];
#pragma unroll
          for (int p = 0; p < 21; p++) acc[p] = fmaf(wv, xv[p + kx], acc[p]);
        }
      }
    }
    __syncthreads();
  }
  float bv = bias[oc];
  float* op = &hid[((size_t)(n * 512 + oc) * 50 + oh) * 84 + ow0];
#pragma unroll
  for (int p = 0; p < 21; p++) { float v = acc[p] + bv; op[p] = v > 0.f ? v : 0.f; }
}

// ---------------- 1x1 heads (18 score + 36 loc) + fg softmax ----------------
__global__ __launch_bounds__(256) void k_head(const float* __restrict__ hid,
    const float* __restrict__ sw, const float* __restrict__ sb,
    const float* __restrict__ lww, const float* __restrict__ lb,
    float* __restrict__ out, float* __restrict__ fg) {
  const int tid = threadIdx.x;
  const int P0 = blockIdx.x * 256;
  const int P = P0 + tid;
  __shared__ float xt[32 * 256];
  __shared__ float wt[32 * 56];
  float acc[54];
#pragma unroll
  for (int o = 0; o < 54; o++) acc[o] = 0.f;

  for (int c0 = 0; c0 < 512; c0 += 32) {
    for (int i = tid; i < 32 * 256; i += 256) {
      int c = i >> 8; int lp = i & 255;
      int PP = P0 + lp;
      float v = 0.f;
      if (PP < N_BATCH * NPIX) {
        int n = PP / NPIX; int p = PP % NPIX;
        v = hid[(size_t)(n * 512 + c0 + c) * NPIX + p];
      }
      xt[c * 256 + lp] = v;
    }
    for (int i = tid; i < 32 * 54; i += 256) {
      int c = i / 54; int o = i % 54;
      wt[c * 56 + o] = (o < 18) ? sw[o * 512 + c0 + c] : lww[(o - 18) * 512 + c0 + c];
    }
    __syncthreads();
#pragma unroll 4
    for (int c = 0; c < 32; c++) {
      float xv = xt[c * 256 + tid];
      const float* wp = &wt[c * 56];
#pragma unroll
      for (int o = 0; o < 54; o++) acc[o] = fmaf(xv, wp[o], acc[o]);
    }
    __syncthreads();
  }

  if (P < N_BATCH * NPIX) {
    int n = P / NPIX; int p = P % NPIX;
    float raw[18];
#pragma unroll
    for (int o = 0; o < 18; o++) raw[o] = acc[o] + sb[o];
    size_t sbase = OFF_SCORES + ((size_t)n * KA + (size_t)p * 9) * 2;
#pragma unroll
    for (int o = 0; o < 18; o++) out[sbase + o] = raw[o];
    size_t lbase = OFF_LOCS + ((size_t)n * KA + (size_t)p * 9) * 4;
#pragma unroll
    for (int o = 0; o < 36; o++) out[lbase + o] = acc[18 + o] + lb[o];
#pragma unroll
    for (int a = 0; a < 9; a++) {
      float r0 = raw[2 * a], r1 = raw[2 * a + 1];
      float m = fmaxf(r0, r1);
      float e0 = expf(r0 - m), e1 = expf(r1 - m);
      fg[(size_t)n * KA + p * 9 + a] = e1 / (e0 + e1);
    }
  }
}

// ---------------- roi prep: loc2bbox + clip + size filter + sortable key ----------------
__global__ void k_prep(const float* __restrict__ out, const float* __restrict__ fg,
    const int* __restrict__ ihp, const int* __restrict__ iwp,
    float4* __restrict__ roi, u64* __restrict__ items) {
  int idx = blockIdx.x * 256 + threadIdx.x;
  if (idx >= N_BATCH * KA) return;
  int b = idx / KA; int k = idx % KA;
  float4 A = ((const float4*)out)[OFF_ANCH / 4 + k];
  float4 L = ((const float4*)out)[OFF_LOCS / 4 + (size_t)b * KA + k];
  float imh = (float)ihp[0], imw = (float)iwp[0];
  float h = A.z - A.x, w = A.w - A.y;
  float yc = A.x + 0.5f * h, xc = A.y + 0.5f * w;
  float cy = L.x * h + yc, cx = L.y * w + xc;
  float nh = expf(L.z) * h, nw = expf(L.w) * w;
  float y1 = cy - 0.5f * nh, x1 = cx - 0.5f * nw;
  float y2 = cy + 0.5f * nh, x2 = cx + 0.5f * nw;
  y1 = fminf(fmaxf(y1, 0.f), imh); y2 = fminf(fmaxf(y2, 0.f), imh);
  x1 = fminf(fmaxf(x1, 0.f), imw); x2 = fminf(fmaxf(x2, 0.f), imw);
  float hs = y2 - y1, wsz = x2 - x1;
  bool valid = (hs >= 16.f) && (wsz >= 16.f);
  float sc = valid ? fg[idx] : NEGV;
  u32 u = __float_as_uint(sc);
  u32 key = (u & 0x80000000u) ? ~u : (u | 0x80000000u);
  roi[(size_t)b * KA + k] = make_float4(y1, x1, y2, x2);
  items[(size_t)b * KA + k] = ((u64)key << 32) | (u32)(~(u32)k);
}

// ---------------- per-batch: radix-select top 6000 + bitonic sort ----------------
__global__ __launch_bounds__(1024) void k_select(const u64* __restrict__ items,
    const float4* __restrict__ roi, u64* __restrict__ sitems, float4* __restrict__ sbox) {
  const int b = blockIdx.x;
  const int tid = threadIdx.x;
  const u64* it = items + (size_t)b * KA;
  __shared__ u64 arr[8192];
  __shared__ u32 hist[256];
  __shared__ u32 sh_need, sh_prefix, sh_cnt;
  if (tid == 0) { sh_need = N_PRE; sh_prefix = 0; sh_cnt = 0; }

  // 4-pass byte-wise radix select on high 32 bits (find kth=6000th largest key)
  for (int s = 3; s >= 0; s--) {
    for (int i = tid; i < 256; i += 1024) hist[i] = 0;
    __syncthreads();
    u32 prefix = sh_prefix;
    int t = 3 - s;
    for (int i = tid; i < KA; i += 1024) {
      u32 key = (u32)(it[i] >> 32);
      bool match = (t == 0) || ((key >> ((s + 1) * 8)) == prefix);
      if (match) atomicAdd(&hist[(key >> (s * 8)) & 255], 1u);
    }
    __syncthreads();
    if (tid == 0) {
      u32 need = sh_need; int chosen = 0;
      for (int bb = 255; bb >= 0; bb--) {
        if (need <= hist[bb]) { chosen = bb; break; }
        need -= hist[bb];
      }
      sh_need = need;
      sh_prefix = (prefix << 8) | (u32)chosen;
    }
    __syncthreads();
  }
  u32 kth = sh_prefix;

  // compact all items with key >= kth (>= 6000 of them; ties resolved by sort)
  for (int i = tid; i < KA; i += 1024) {
    u64 v = it[i];
    if ((u32)(v >> 32) >= kth) {
      u32 pos = atomicAdd(&sh_cnt, 1u);
      if (pos < 8192) arr[pos] = v;
    }
  }
  __syncthreads();
  u32 T = sh_cnt; if (T > 8192) T = 8192;
  for (int i = (int)T + tid; i < 8192; i += 1024) arr[i] = 0ull;

  // bitonic sort, descending (key desc, then ~idx desc == idx asc)
  for (u32 k = 2; k <= 8192; k <<= 1) {
    for (u32 j = k >> 1; j > 0; j >>= 1) {
      __syncthreads();
      for (u32 i = tid; i < 8192; i += 1024) {
        u32 l = i ^ j;
        if (l > i) {
          u64 a = arr[i], c = arr[l];
          bool dir = ((i & k) == 0);
          if ((a < c) == dir) { arr[i] = c; arr[l] = a; }
        }
      }
    }
  }
  __syncthreads();
  for (int i = tid; i < N_PRE; i += 1024) {
    u64 v = arr[i];
    sitems[(size_t)b * N_PRE + i] = v;
    u32 kk = ~(u32)(v & 0xffffffffull);
    float4 bx = make_float4(0, 0, 0, 0);
    if (kk < KA) bx = roi[(size_t)b * KA + kk];
    sbox[(size_t)b * N_PRE + i] = bx;
  }
}

// ---------------- NMS suppression bitmask (upper-triangle 64x64 blocks) ----------------
__global__ __launch_bounds__(64) void k_mask(const float4* __restrict__ sbox,
    u64* __restrict__ mask) {
  const int cb = blockIdx.x, rb = blockIdx.y, b = blockIdx.z;
  if (cb < rb) return;
  const int tid = threadIdx.x;
  __shared__ float4 cbx[64];
  __shared__ float carea[64];
  int col0 = cb * 64;
  int c = col0 + tid;
  float4 v = (c < N_PRE) ? sbox[(size_t)b * N_PRE + c] : make_float4(0, 0, 0, 0);
  cbx[tid] = v;
  carea[tid] = (v.z - v.x) * (v.w - v.y);
  __syncthreads();
  int row = rb * 64 + tid;
  if (row >= N_PRE) return;
  float4 r = sbox[(size_t)b * N_PRE + row];
  float rarea = (r.z - r.x) * (r.w - r.y);
  u64 word = 0ull;
  for (int j = 0; j < 64; j++) {
    int cc = col0 + j;
    if (cc > row && cc < N_PRE) {
      float4 q = cbx[j];
      float ty = fmaxf(r.x, q.x), tx = fmaxf(r.y, q.y);
      float by = fminf(r.z, q.z), bx = fminf(r.w, q.w);
      float ihh = fmaxf(by - ty, 0.f), iww = fmaxf(bx - tx, 0.f);
      float inter = ihh * iww;
      float iou = inter / (rarea + carea[j] - inter + 1e-9f);
      if (iou > NMS_T) word |= (1ull << j);
    }
  }
  mask[((size_t)b * N_PRE + row) * NWORDS + cb] = word;
}

// ---------------- sequential NMS reduce + write rois/roi_indices ----------------
__global__ __launch_bounds__(64) void k_nms_out(const u64* __restrict__ sitems,
    const float4* __restrict__ sbox, const u64* __restrict__ mask,
    float* __restrict__ out) {
  const int b = blockIdx.x;
  const int lane = threadIdx.x;
  __shared__ u64 remv[NWORDS];
  __shared__ u32 keep[N_POST];
  for (int i = lane; i < NWORDS; i += 64) remv[i] = 0ull;
  __syncthreads();
  u32 keyneg = ~__float_as_uint(NEGV);  // NEGV<0 so key = ~bits
  int kc = 0;
  for (int g = 0; g < NWORDS && kc < N_POST; g++) {
    int row0 = g * 64;
    int myrow = row0 + lane;
    bool pre = true;
    if (myrow < N_PRE) {
      u32 key = (u32)(sitems[(size_t)b * N_PRE + myrow] >> 32);
      pre = (key == keyneg) || (key == 0u);
    }
    u64 preM = __ballot(pre);
    u64 done = 0ull;
    while (kc < N_POST) {
      u64 cur = remv[g] | preM | done;
      if (cur == ~0ull) break;
      int bit = __ffsll((long long)(~cur)) - 1;
      int row = row0 + bit;
      done |= (1ull << bit);
      if (lane == 0) keep[kc] = (u32)row;
      kc++;
      for (int cb2 = g + lane; cb2 < NWORDS; cb2 += 64) {
        u64 w = mask[((size_t)b * N_PRE + row) * NWORDS + cb2];
        remv[cb2] |= w;
      }
      __syncthreads();
    }
  }
  __syncthreads();
  for (int r2 = lane; r2 < N_POST; r2 += 64) {
    float4 bx = make_float4(0, 0, 0, 0);
    if (r2 < kc) bx = sbox[(size_t)b * N_PRE + keep[r2]];
    ((float4*)out)[OFF_ROIS / 4 + (size_t)b * N_POST + r2] = bx;
    out[OFF_RIDX + (size_t)b * N_POST + r2] = (float)b;
  }
}

// ---------------- launch ----------------
extern "C" void kernel_launch(void* const* d_in, const int* in_sizes, int n_in,
                              void* d_out, int out_size, void* d_ws, size_t ws_size,
                              hipStream_t stream) {
  const float* x   = (const float*)d_in[0];
  const float* c1w = (const float*)d_in[1];
  const float* c1b = (const float*)d_in[2];
  const float* sw  = (const float*)d_in[3];
  const float* sb  = (const float*)d_in[4];
  const float* lw  = (const float*)d_in[5];
  const float* lb  = (const float*)d_in[6];
  const int* ih    = (const int*)d_in[7];
  const int* iw    = (const int*)d_in[8];
  float* out = (float*)d_out;
  char* wsb = (char*)d_ws;

  float* hid   = (float*)(wsb + WS_HID);
  float* fg    = (float*)(wsb + WS_FG);
  float4* roi  = (float4*)(wsb + WS_ROI);
  u64* items   = (u64*)(wsb + WS_ITEMS);
  u64* sitems  = (u64*)(wsb + WS_SITEMS);
  float4* sbox = (float4*)(wsb + WS_SBOX);
  u64* maskp   = (u64*)(wsb + WS_MASK);

  hipLaunchKernelGGL(k_anchor, dim3((KA + 255) / 256), dim3(256), 0, stream, out);
  hipLaunchKernelGGL(k_conv1, dim3(8, 50, 2), dim3(256), 0, stream, x, c1w, c1b, hid);
  hipLaunchKernelGGL(k_head, dim3((N_BATCH * NPIX + 255) / 256), dim3(256), 0, stream,
                     hid, sw, sb, lw, lb, out, fg);
  hipLaunchKernelGGL(k_prep, dim3((N_BATCH * KA + 255) / 256), dim3(256), 0, stream,
                     out, fg, ih, iw, roi, items);
  hipLaunchKernelGGL(k_select, dim3(2), dim3(1024), 0, stream, items, roi, sitems, sbox);
  hipLaunchKernelGGL(k_mask, dim3(NWORDS, NWORDS, 2), dim3(64), 0, stream, sbox, maskp);
  hipLaunchKernelGGL(k_nms_out, dim3(2), dim3(64), 0, stream, sitems, sbox, maskp, out);
}